// Round 4
// baseline (336.555 us; speedup 1.0000x reference)
//
#include <hip/hip_runtime.h>

#define N 4096
#define C 64
#define B 4

typedef __attribute__((ext_vector_type(8))) short short8;
typedef __attribute__((ext_vector_type(4))) short s16x4;
typedef __attribute__((ext_vector_type(4))) float f32x4;
typedef unsigned long long u64;

#define MFMA16(a, b, c) __builtin_amdgcn_mfma_f32_16x16x32_bf16(a, b, c, 0, 0, 0)

__device__ __forceinline__ short f2bf(float f) {
    unsigned u = __builtin_bit_cast(unsigned, f);
    u += 0x7fffu + ((u >> 16) & 1u);   // RNE; inputs finite
    return (short)(u >> 16);
}

// -------- adjacency bitmask: adj = (0<d<0.5) | eye, one uint64 per (i, j/64) --------
__global__ __launch_bounds__(256) void mask_kernel(const float* __restrict__ dist,
                                                   u64* __restrict__ msk) {
    const int wave = threadIdx.x >> 6, lane = threadIdx.x & 63;
    const int i = blockIdx.x * 4 + wave;
    const float* row = dist + (size_t)i * N;
#pragma unroll 8
    for (int jb = 0; jb < N / 64; jb++) {
        float d = row[jb * 64 + lane];               // coalesced 256B per wave
        u64 m = __ballot(d > 0.f && d < 0.5f);
        int dj = i - jb * 64;
        if (dj >= 0 && dj < 64) m |= (1ull << dj);   // diagonal
        if (lane == 0) msk[(size_t)i * (N / 64) + jb] = m;
    }
}

// -------- Phase A: projection (coalesced writes only) --------
__global__ __launch_bounds__(256) void proj_kernel(
    const float* __restrict__ x,       // B,N,C
    const float* __restrict__ proj_w,  // N,C,C
    const float* __restrict__ proj_b,  // N,C
    const float* __restrict__ a_w,     // N,2C
    short* __restrict__ h_bf,          // B,N,C
    short* __restrict__ a_srcb,        // N,C
    float* __restrict__ e2)            // B,N
{
    __shared__ float lds_x[B][C];
    __shared__ float lds_acc[4][B][C];

    const int tid = threadIdx.x;
    const int wave = tid >> 6;
    const int lane = tid & 63;
    const int n = blockIdx.x;

    lds_x[wave][lane] = x[((size_t)wave * N + n) * C + lane];  // wave==b
    __syncthreads();

    const int o4 = (lane & 15) * 4;
    const int cl = lane >> 4;
    const float* Wn = proj_w + (size_t)n * C * C;

    float4 acc[B];
#pragma unroll
    for (int b = 0; b < B; b++) acc[b] = make_float4(0.f, 0.f, 0.f, 0.f);

#pragma unroll
    for (int i = 0; i < 4; i++) {
        int c = wave * 16 + i * 4 + cl;
        float4 wv = *(const float4*)(Wn + c * C + o4);  // wave reads 1KB contiguous
#pragma unroll
        for (int b = 0; b < B; b++) {
            float xc = lds_x[b][c];
            acc[b].x = fmaf(xc, wv.x, acc[b].x);
            acc[b].y = fmaf(xc, wv.y, acc[b].y);
            acc[b].z = fmaf(xc, wv.z, acc[b].z);
            acc[b].w = fmaf(xc, wv.w, acc[b].w);
        }
    }
#pragma unroll
    for (int b = 0; b < B; b++) {
#pragma unroll
        for (int off = 16; off < 64; off <<= 1) {
            acc[b].x += __shfl_xor(acc[b].x, off, 64);
            acc[b].y += __shfl_xor(acc[b].y, off, 64);
            acc[b].z += __shfl_xor(acc[b].z, off, 64);
            acc[b].w += __shfl_xor(acc[b].w, off, 64);
        }
        if (lane < 16) *(float4*)(&lds_acc[wave][b][o4]) = acc[b];
    }
    __syncthreads();

    {
        const int b = wave, o = lane;
        float hval = proj_b[(size_t)n * C + o] + lds_acc[0][b][o] + lds_acc[1][b][o] +
                     lds_acc[2][b][o] + lds_acc[3][b][o];
        float adst = a_w[(size_t)n * (2 * C) + C + o];
        h_bf[((size_t)b * N + n) * C + o] = f2bf(hval);
        float prod = hval * adst;
#pragma unroll
        for (int off = 32; off; off >>= 1) prod += __shfl_xor(prod, off, 64);
        if (lane == 0) e2[b * N + n] = prod;
        if (tid < C) a_srcb[(size_t)n * C + tid] = f2bf(a_w[(size_t)n * (2 * C) + tid]);
    }
}

// -------- h (B,N,C) -> hT (B,C,N), both sides coalesced via LDS tile --------
__global__ __launch_bounds__(256) void transpose_kernel(const short* __restrict__ h_bf,
                                                        short* __restrict__ hT_bf) {
    __shared__ short tile[64][72];
    const int t = threadIdx.x;
    const int b = blockIdx.y;
    const int n0 = blockIdx.x * 64;
    {
        int r = t >> 2, cs = (t & 3) * 16;
        const short* src = h_bf + ((size_t)b * N + n0 + r) * C + cs;
#pragma unroll
        for (int q = 0; q < 4; q++)
            *(s16x4*)&tile[r][cs + q * 4] = *(const s16x4*)(src + q * 4);
    }
    __syncthreads();
    {
        int c = t >> 2, ns = (t & 3) * 16;
        short v[16];
#pragma unroll
        for (int k = 0; k < 16; k++) v[k] = tile[ns + k][c];
        short* dst = hT_bf + (size_t)b * C * N + (size_t)c * N + n0 + ns;
        *(short8*)dst = *(short8*)&v[0];
        *(short8*)(dst + 8) = *(short8*)&v[8];
    }
}

// -------- Phase B pass 1: flash attention, transposed-S scheme --------
// S^T via MFMA(A=a_src, B=h_i): lane holds row i=cl, 16 j-values in (t, reg).
// Softmax reductions are lane-local + 2 swizzles; state (m,l) per lane.
__global__ __launch_bounds__(256) void attn_kernel(
    const u64* __restrict__ msk,       // N x N/64 adjacency bits
    const short* __restrict__ h_bf,    // B,N,C
    const short* __restrict__ hT_bf,   // B,C,N
    const short* __restrict__ a_srcb,  // N,C
    const float* __restrict__ e2,      // B,N
    float* __restrict__ part_y,        // [S,B,N,C] or out [B,N,C] if mode
    float* __restrict__ part_m,        // [S,B,N]
    float* __restrict__ part_l,        // [S,B,N]
    int JS, int mode)
{
    __shared__ short lds_p[4][16 * 72];   // wave-private P tiles
    __shared__ float lds_e2[4][512];      // wave-private e2 stripe
    __shared__ float lds_bc[4][32];       // wave-private alpha/l broadcast

    const int tid = threadIdx.x;
    const int wave = tid >> 6;
    const int lane = tid & 63;
    const int cl = lane & 15;   // row i (local)
    const int rg = lane >> 4;
    const int b = wave;
    const int i0 = blockIdx.x * 16;
    const int jbeg = blockIdx.y * JS;
    const bool e2lds = (JS <= 512);

    if (e2lds) {
        for (int q = lane * 4; q < JS; q += 256)
            *(f32x4*)&lds_e2[wave][q] = *(const f32x4*)(e2 + (size_t)b * N + jbeg + q);
    }

    // B-operand frags: h_i rows (n = i = cl, k = c)
    const short* hrow = h_bf + ((size_t)b * N + i0 + cl) * C;
    short8 bf0 = *(const short8*)(hrow + rg * 8);
    short8 bf1 = *(const short8*)(hrow + 32 + rg * 8);

    const u64* mrow = msk + (size_t)(i0 + cl) * (N / 64);

    f32x4 yacc[4];
#pragma unroll
    for (int t = 0; t < 4; t++) { f32x4 z = {0.f, 0.f, 0.f, 0.f}; yacc[t] = z; }
    float m_s = -1e30f;   // state for row i = cl (replicated over rg groups)
    float l_s = 0.f;

    for (int j0 = jbeg; j0 < jbeg + JS; j0 += 64) {
        u64 mbits = mrow[j0 >> 6];   // one load/lane: row cl's 64 adjacency bits

        // ---- S^T = A_src @ H_i^T : st[t][r] = S[i=cl][j = t*16 + rg*4 + r] ----
        f32x4 st[4];
#pragma unroll
        for (int t = 0; t < 4; t++) {
            const short* arow = a_srcb + (size_t)(j0 + t * 16 + cl) * C + rg * 8;
            short8 a0 = *(const short8*)(arow);
            short8 a1 = *(const short8*)(arow + 32);
            f32x4 z = {0.f, 0.f, 0.f, 0.f};
            z = MFMA16(a0, bf0, z);
            z = MFMA16(a1, bf1, z);
            st[t] = z;
        }

        // ---- epilogue: +e2, leaky, mask; lane-local max ----
        unsigned wlo = (unsigned)mbits, whi = (unsigned)(mbits >> 32);
        float mx = -1e30f;
#pragma unroll
        for (int t = 0; t < 4; t++) {
            f32x4 e2q;
            if (e2lds) e2q = *(const f32x4*)&lds_e2[wave][j0 - jbeg + t * 16 + rg * 4];
            else       e2q = *(const f32x4*)(e2 + (size_t)b * N + j0 + t * 16 + rg * 4);
            unsigned w = (t < 2) ? wlo : whi;
            unsigned sh = (t & 1) * 16 + rg * 4;
#pragma unroll
            for (int r = 0; r < 4; r++) {
                float sv = st[t][r] + e2q[r];
                sv = (sv >= 0.f) ? sv : 0.01f * sv;
                sv = ((w >> (sh + r)) & 1u) ? sv : -1e15f;
                st[t][r] = sv;
                mx = fmaxf(mx, sv);
            }
        }

        // ---- online softmax: 2+2 swizzles total ----
        mx = fmaxf(mx, __shfl_xor(mx, 16, 64));
        mx = fmaxf(mx, __shfl_xor(mx, 32, 64));
        float mnew = fmaxf(m_s, mx);
        float alpha = __expf(m_s - mnew);
        m_s = mnew;
        float ps = 0.f;
#pragma unroll
        for (int t = 0; t < 4; t++)
#pragma unroll
            for (int r = 0; r < 4; r++) {
                float pv = __expf(st[t][r] - mnew);
                st[t][r] = pv;
                ps += pv;
            }
        ps += __shfl_xor(ps, 16, 64);
        ps += __shfl_xor(ps, 32, 64);
        l_s = l_s * alpha + ps;

        // ---- broadcast alpha (lane cl-indexed) to yacc row-layout ----
        if (lane < 16) lds_bc[wave][lane] = alpha;
        f32x4 a4 = *(const f32x4*)&lds_bc[wave][rg * 4];
#pragma unroll
        for (int t = 0; t < 4; t++)
#pragma unroll
            for (int r = 0; r < 4; r++) yacc[t][r] *= a4[r];

        // ---- P -> LDS (rows of P; 4 j-consecutive bf16 per store) ----
        short* lp = lds_p[wave];
#pragma unroll
        for (int t = 0; t < 4; t++) {
            s16x4 pk;
#pragma unroll
            for (int r = 0; r < 4; r++) pk[r] = f2bf(st[t][r]);
            *(s16x4*)(lp + cl * 72 + t * 16 + rg * 4) = pk;
        }
        short8 pa0 = *(const short8*)(lp + cl * 72 + rg * 8);
        short8 pa1 = *(const short8*)(lp + cl * 72 + 32 + rg * 8);

        // ---- Y += P @ H_j ----
#pragma unroll
        for (int t = 0; t < 4; t++) {
            const short* hc = hT_bf + (size_t)b * C * N + (size_t)(t * 16 + cl) * N + j0 + rg * 8;
            short8 h0 = *(const short8*)(hc);
            short8 h1 = *(const short8*)(hc + 32);
            yacc[t] = MFMA16(pa0, h0, yacc[t]);
            yacc[t] = MFMA16(pa1, h1, yacc[t]);
        }
    }

    // ---- broadcast l to row-layout; write ----
    if (lane < 16) lds_bc[wave][16 + lane] = l_s;
    f32x4 l4 = *(const f32x4*)&lds_bc[wave][16 + rg * 4];

    if (mode) {
#pragma unroll
        for (int t = 0; t < 4; t++)
#pragma unroll
            for (int r = 0; r < 4; r++)
                part_y[((size_t)b * N + i0 + rg * 4 + r) * C + t * 16 + cl] =
                    yacc[t][r] / l4[r];
    } else {
        size_t sb = (size_t)(blockIdx.y * B + b) * N;
#pragma unroll
        for (int t = 0; t < 4; t++)
#pragma unroll
            for (int r = 0; r < 4; r++)
                part_y[(sb + i0 + rg * 4 + r) * C + t * 16 + cl] = yacc[t][r];
        if (lane < 16) {
            part_m[sb + i0 + lane] = m_s;
            part_l[sb + i0 + lane] = l_s;
        }
    }
}

// -------- Phase B pass 2: merge stripes --------
__global__ __launch_bounds__(256) void combine_kernel(
    const float* __restrict__ part_y, const float* __restrict__ part_m,
    const float* __restrict__ part_l, float* __restrict__ out, int S)
{
    int g = blockIdx.x * 256 + threadIdx.x;
    int c = g & 63;
    int row = (g >> 6) & (N - 1);
    int b = g >> 18;
    int bn = b * N + row;
    float m = -1e30f;
    for (int s = 0; s < S; s++) m = fmaxf(m, part_m[s * (B * N) + bn]);
    float l = 0.f, y = 0.f;
    for (int s = 0; s < S; s++) {
        float w = __expf(part_m[s * (B * N) + bn] - m);
        l += part_l[s * (B * N) + bn] * w;
        y += part_y[((size_t)s * B * N + bn) * C + c] * w;
    }
    out[g] = y / l;
}

extern "C" void kernel_launch(void* const* d_in, const int* in_sizes, int n_in,
                              void* d_out, int out_size, void* d_ws, size_t ws_size,
                              hipStream_t stream) {
    const float* x      = (const float*)d_in[0];
    const float* dist   = (const float*)d_in[1];
    const float* proj_w = (const float*)d_in[2];
    const float* proj_b = (const float*)d_in[3];
    const float* a_w    = (const float*)d_in[4];
    float* out = (float*)d_out;

    char* ws = (char*)d_ws;
    short* h_bf   = (short*)(ws);                              // 2 MB
    short* hT_bf  = (short*)(ws + (2u << 20));                 // 2 MB
    short* a_srcb = (short*)(ws + (4u << 20));                 // 512 KB
    float* e2     = (float*)(ws + (4u << 20) + (512u << 10));  // 64 KB
    u64*   msk    = (u64*)  (ws + (5u << 20));                 // 2 MB
    float* part_m = (float*)(ws + (7u << 20));                 // 512 KB (S=8)
    float* part_l = (float*)(ws + (7u << 20) + (512u << 10));  // 512 KB
    float* part_y = (float*)(ws + (8u << 20));                 // S * 4 MB

    proj_kernel<<<N, 256, 0, stream>>>(x, proj_w, proj_b, a_w, h_bf, a_srcb, e2);
    transpose_kernel<<<dim3(N / 64, B), 256, 0, stream>>>(h_bf, hT_bf);
    mask_kernel<<<N / 4, 256, 0, stream>>>(dist, msk);

    int S = 8;
    while (S > 1 && (8u << 20) + (size_t)S * B * N * C * 4 > ws_size) S >>= 1;
    bool direct = ((8u << 20) + (size_t)B * N * C * 4 > ws_size);

    if (direct) {
        attn_kernel<<<dim3(N / 16, 1), 256, 0, stream>>>(
            msk, h_bf, hT_bf, a_srcb, e2, out, part_m, part_l, N, 1);
    } else {
        attn_kernel<<<dim3(N / 16, S), 256, 0, stream>>>(
            msk, h_bf, hT_bf, a_srcb, e2, part_y, part_m, part_l, N / S, 0);
        combine_kernel<<<(B * N * C) / 256, 256, 0, stream>>>(part_y, part_m, part_l, out, S);
    }
}

// Round 5
// 280.659 us; speedup vs baseline: 1.1992x; 1.1992x over previous
//
#include <hip/hip_runtime.h>

#define N 4096
#define C 64
#define B 4

typedef __attribute__((ext_vector_type(8))) short short8;
typedef __attribute__((ext_vector_type(4))) short s16x4;
typedef __attribute__((ext_vector_type(4))) float f32x4;
typedef unsigned long long u64;

#define MFMA16(a, b, c) __builtin_amdgcn_mfma_f32_16x16x32_bf16(a, b, c, 0, 0, 0)

__device__ __forceinline__ short f2bf(float f) {
    unsigned u = __builtin_bit_cast(unsigned, f);
    u += 0x7fffu + ((u >> 16) & 1u);   // RNE; inputs finite
    return (short)(u >> 16);
}

// -------- adjacency bitmask: adj = (0<d<0.5) | eye, one uint64 per (i, j/64) --------
__global__ __launch_bounds__(256) void mask_kernel(const float* __restrict__ dist,
                                                   u64* __restrict__ msk) {
    const int wave = threadIdx.x >> 6, lane = threadIdx.x & 63;
    const int i = blockIdx.x * 4 + wave;
    const float* row = dist + (size_t)i * N;
#pragma unroll 8
    for (int jb = 0; jb < N / 64; jb++) {
        float d = row[jb * 64 + lane];               // coalesced 256B per wave
        u64 m = __ballot(d > 0.f && d < 0.5f);
        int dj = i - jb * 64;
        if (dj >= 0 && dj < 64) m |= (1ull << dj);   // diagonal
        if (lane == 0) msk[(size_t)i * (N / 64) + jb] = m;
    }
}

// -------- Phase A v3: W staged to LDS; lane = output channel; no cross-lane reduce --------
// 4 nodes per block (wave w -> node). Per wave: 16KB W -> LDS, then 64-step dot from LDS.
__global__ __launch_bounds__(256) void proj_kernel(
    const float* __restrict__ x,       // B,N,C
    const float* __restrict__ proj_w,  // N,C,C
    const float* __restrict__ proj_b,  // N,C
    const float* __restrict__ a_w,     // N,2C
    short* __restrict__ h_bf,          // B,N,C
    short* __restrict__ a_srcb,        // N,C
    float* __restrict__ e2)            // B,N
{
    __shared__ float lds_w[4][64 * 64];   // 64 KB
    __shared__ float lds_x[4][B][C];      // 4 KB

    const int tid = threadIdx.x;
    const int wave = tid >> 6;
    const int lane = tid & 63;
    const int n = blockIdx.x * 4 + wave;
    const float* Wn = proj_w + (size_t)n * C * C;

    // stage W: 16 independent float4 loads in flight, then b128 LDS writes
    float4 wbuf[16];
#pragma unroll
    for (int it = 0; it < 16; it++)
        wbuf[it] = *(const float4*)(Wn + it * 256 + lane * 4);
    // stage x while W loads are in flight
#pragma unroll
    for (int b = 0; b < B; b++)
        lds_x[wave][b][lane] = x[((size_t)b * N + n) * C + lane];
#pragma unroll
    for (int it = 0; it < 16; it++)
        *(float4*)&lds_w[wave][it * 256 + lane * 4] = wbuf[it];

    const int o = lane;
    float acc[B];
    float pb = proj_b[(size_t)n * C + o];
#pragma unroll
    for (int b = 0; b < B; b++) acc[b] = pb;

    // wave-private LDS: compiler orders write->read via lgkmcnt; no barrier needed
#pragma unroll 4
    for (int c4 = 0; c4 < C; c4 += 4) {
        f32x4 xq[B];
#pragma unroll
        for (int b = 0; b < B; b++) xq[b] = *(const f32x4*)&lds_x[wave][b][c4];
#pragma unroll
        for (int k = 0; k < 4; k++) {
            float w = lds_w[wave][(c4 + k) * C + o];   // banks = o%32: 2-way, free
#pragma unroll
            for (int b = 0; b < B; b++) acc[b] = fmaf(xq[b][k], w, acc[b]);
        }
    }

    float adst = a_w[(size_t)n * (2 * C) + C + o];
    a_srcb[(size_t)n * C + o] = f2bf(a_w[(size_t)n * (2 * C) + o]);
#pragma unroll
    for (int b = 0; b < B; b++) {
        h_bf[((size_t)b * N + n) * C + o] = f2bf(acc[b]);
        float prod = acc[b] * adst;
#pragma unroll
        for (int off = 32; off; off >>= 1) prod += __shfl_xor(prod, off, 64);
        if (lane == 0) e2[b * N + n] = prod;
    }
}

// -------- h (B,N,C) -> hT (B,C,N), both sides coalesced via LDS tile --------
__global__ __launch_bounds__(256) void transpose_kernel(const short* __restrict__ h_bf,
                                                        short* __restrict__ hT_bf) {
    __shared__ short tile[64][72];
    const int t = threadIdx.x;
    const int b = blockIdx.y;
    const int n0 = blockIdx.x * 64;
    {
        int r = t >> 2, cs = (t & 3) * 16;
        const short* src = h_bf + ((size_t)b * N + n0 + r) * C + cs;
#pragma unroll
        for (int q = 0; q < 4; q++)
            *(s16x4*)&tile[r][cs + q * 4] = *(const s16x4*)(src + q * 4);
    }
    __syncthreads();
    {
        int c = t >> 2, ns = (t & 3) * 16;
        short v[16];
#pragma unroll
        for (int k = 0; k < 16; k++) v[k] = tile[ns + k][c];
        short* dst = hT_bf + (size_t)b * C * N + (size_t)c * N + n0 + ns;
        *(short8*)dst = *(short8*)&v[0];
        *(short8*)(dst + 8) = *(short8*)&v[8];
    }
}

// -------- Phase B v5: flash attention, 32 i-rows per wave (2 subtiles share loads) --------
__global__ __launch_bounds__(256) void attn_kernel(
    const u64* __restrict__ msk,       // N x N/64 adjacency bits
    const short* __restrict__ h_bf,    // B,N,C
    const short* __restrict__ hT_bf,   // B,C,N
    const short* __restrict__ a_srcb,  // N,C
    const float* __restrict__ e2,      // B,N
    float* __restrict__ part_y,        // [S,B,N,C] or out [B,N,C] if mode
    float* __restrict__ part_m,        // [S,B,N]
    float* __restrict__ part_l,        // [S,B,N]
    int JS, int mode)
{
    __shared__ short lds_p[4][16 * 72];   // wave-private P tile (reused by both subtiles)
    __shared__ float lds_e2[4][512];      // wave-private e2 stripe
    __shared__ float lds_bc[4][64];       // wave-private alpha/l broadcast

    const int tid = threadIdx.x;
    const int wave = tid >> 6;
    const int lane = tid & 63;
    const int cl = lane & 15;   // row i (local, within subtile)
    const int rg = lane >> 4;
    const int b = wave;
    const int i0 = blockIdx.x * 32;
    const int jbeg = blockIdx.y * JS;
    const bool e2lds = (JS <= 512);

    if (e2lds) {
        for (int q = lane * 4; q < JS; q += 256)
            *(f32x4*)&lds_e2[wave][q] = *(const f32x4*)(e2 + (size_t)b * N + jbeg + q);
    }

    // B-operand frags for both i-subtiles
    short8 bfr[2][2];
#pragma unroll
    for (int u = 0; u < 2; u++) {
        const short* hrow = h_bf + ((size_t)b * N + i0 + u * 16 + cl) * C;
        bfr[u][0] = *(const short8*)(hrow + rg * 8);
        bfr[u][1] = *(const short8*)(hrow + 32 + rg * 8);
    }

    const u64* mr[2] = {msk + (size_t)(i0 + cl) * (N / 64),
                        msk + (size_t)(i0 + 16 + cl) * (N / 64)};

    f32x4 yacc[2][4];
#pragma unroll
    for (int u = 0; u < 2; u++)
#pragma unroll
        for (int t = 0; t < 4; t++) { f32x4 z = {0.f, 0.f, 0.f, 0.f}; yacc[u][t] = z; }
    float m_s[2] = {-1e30f, -1e30f};
    float l_s[2] = {0.f, 0.f};

    for (int j0 = jbeg; j0 < jbeg + JS; j0 += 64) {
        // ---- shared loads: a-frags (8 b128), e2 quads, masks ----
        short8 a0[4], a1[4];
#pragma unroll
        for (int t = 0; t < 4; t++) {
            const short* arow = a_srcb + (size_t)(j0 + t * 16 + cl) * C + rg * 8;
            a0[t] = *(const short8*)(arow);
            a1[t] = *(const short8*)(arow + 32);
        }
        f32x4 e2q[4];
#pragma unroll
        for (int t = 0; t < 4; t++) {
            if (e2lds) e2q[t] = *(const f32x4*)&lds_e2[wave][j0 - jbeg + t * 16 + rg * 4];
            else       e2q[t] = *(const f32x4*)(e2 + (size_t)b * N + j0 + t * 16 + rg * 4);
        }
        u64 mbits[2] = {mr[0][j0 >> 6], mr[1][j0 >> 6]};

        short8 pa[2][2];
#pragma unroll
        for (int u = 0; u < 2; u++) {
            // ---- S^T: st[t][r] = S[i = i0+u*16+cl][j = j0 + t*16 + rg*4 + r] ----
            f32x4 st[4];
#pragma unroll
            for (int t = 0; t < 4; t++) {
                f32x4 z = {0.f, 0.f, 0.f, 0.f};
                z = MFMA16(a0[t], bfr[u][0], z);
                z = MFMA16(a1[t], bfr[u][1], z);
                st[t] = z;
            }

            unsigned wlo = (unsigned)mbits[u], whi = (unsigned)(mbits[u] >> 32);
            float mx = -1e30f;
#pragma unroll
            for (int t = 0; t < 4; t++) {
                unsigned w = (t < 2) ? wlo : whi;
                unsigned sh = (t & 1) * 16 + rg * 4;
#pragma unroll
                for (int r = 0; r < 4; r++) {
                    float sv = st[t][r] + e2q[t][r];
                    sv = (sv >= 0.f) ? sv : 0.01f * sv;
                    sv = ((w >> (sh + r)) & 1u) ? sv : -1e15f;
                    st[t][r] = sv;
                    mx = fmaxf(mx, sv);
                }
            }

            // ---- online softmax: lane-local + 2 swizzles ----
            mx = fmaxf(mx, __shfl_xor(mx, 16, 64));
            mx = fmaxf(mx, __shfl_xor(mx, 32, 64));
            float mnew = fmaxf(m_s[u], mx);
            float alpha = __expf(m_s[u] - mnew);
            m_s[u] = mnew;
            float ps = 0.f;
#pragma unroll
            for (int t = 0; t < 4; t++)
#pragma unroll
                for (int r = 0; r < 4; r++) {
                    float pv = __expf(st[t][r] - mnew);
                    st[t][r] = pv;
                    ps += pv;
                }
            ps += __shfl_xor(ps, 16, 64);
            ps += __shfl_xor(ps, 32, 64);
            l_s[u] = l_s[u] * alpha + ps;

            if (lane < 16) lds_bc[wave][u * 16 + lane] = alpha;
            f32x4 a4 = *(const f32x4*)&lds_bc[wave][u * 16 + rg * 4];
#pragma unroll
            for (int t = 0; t < 4; t++)
#pragma unroll
                for (int r = 0; r < 4; r++) yacc[u][t][r] *= a4[r];

            // ---- P -> LDS (C-layout rows) -> A-frag ----
            short* lp = lds_p[wave];
#pragma unroll
            for (int t = 0; t < 4; t++) {
                s16x4 pk;
#pragma unroll
                for (int r = 0; r < 4; r++) pk[r] = f2bf(st[t][r]);
                *(s16x4*)(lp + cl * 72 + t * 16 + rg * 4) = pk;
            }
            pa[u][0] = *(const short8*)(lp + cl * 72 + rg * 8);
            pa[u][1] = *(const short8*)(lp + cl * 72 + 32 + rg * 8);
        }

        // ---- Y += P @ H_j : hT loads shared by both subtiles ----
#pragma unroll
        for (int t = 0; t < 4; t++) {
            const short* hc = hT_bf + (size_t)b * C * N + (size_t)(t * 16 + cl) * N + j0 + rg * 8;
            short8 h0 = *(const short8*)(hc);
            short8 h1 = *(const short8*)(hc + 32);
            yacc[0][t] = MFMA16(pa[0][0], h0, yacc[0][t]);
            yacc[0][t] = MFMA16(pa[0][1], h1, yacc[0][t]);
            yacc[1][t] = MFMA16(pa[1][0], h0, yacc[1][t]);
            yacc[1][t] = MFMA16(pa[1][1], h1, yacc[1][t]);
        }
    }

    // ---- epilogue ----
#pragma unroll
    for (int u = 0; u < 2; u++)
        if (lane < 16) lds_bc[wave][32 + u * 16 + lane] = l_s[u];

    if (mode) {
#pragma unroll
        for (int u = 0; u < 2; u++) {
            f32x4 l4 = *(const f32x4*)&lds_bc[wave][32 + u * 16 + rg * 4];
#pragma unroll
            for (int t = 0; t < 4; t++)
#pragma unroll
                for (int r = 0; r < 4; r++)
                    part_y[((size_t)b * N + i0 + u * 16 + rg * 4 + r) * C + t * 16 + cl] =
                        yacc[u][t][r] / l4[r];
        }
    } else {
        size_t sb = (size_t)(blockIdx.y * B + b) * N;
#pragma unroll
        for (int u = 0; u < 2; u++) {
#pragma unroll
            for (int t = 0; t < 4; t++)
#pragma unroll
                for (int r = 0; r < 4; r++)
                    part_y[(sb + i0 + u * 16 + rg * 4 + r) * C + t * 16 + cl] = yacc[u][t][r];
            if (lane < 16) {
                part_m[sb + i0 + u * 16 + lane] = m_s[u];
                part_l[sb + i0 + u * 16 + lane] = l_s[u];
            }
        }
    }
}

// -------- Phase B pass 2: merge stripes --------
__global__ __launch_bounds__(256) void combine_kernel(
    const float* __restrict__ part_y, const float* __restrict__ part_m,
    const float* __restrict__ part_l, float* __restrict__ out, int S)
{
    int g = blockIdx.x * 256 + threadIdx.x;
    int c = g & 63;
    int row = (g >> 6) & (N - 1);
    int b = g >> 18;
    int bn = b * N + row;
    float m = -1e30f;
    for (int s = 0; s < S; s++) m = fmaxf(m, part_m[s * (B * N) + bn]);
    float l = 0.f, y = 0.f;
    for (int s = 0; s < S; s++) {
        float w = __expf(part_m[s * (B * N) + bn] - m);
        l += part_l[s * (B * N) + bn] * w;
        y += part_y[((size_t)s * B * N + bn) * C + c] * w;
    }
    out[g] = y / l;
}

extern "C" void kernel_launch(void* const* d_in, const int* in_sizes, int n_in,
                              void* d_out, int out_size, void* d_ws, size_t ws_size,
                              hipStream_t stream) {
    const float* x      = (const float*)d_in[0];
    const float* dist   = (const float*)d_in[1];
    const float* proj_w = (const float*)d_in[2];
    const float* proj_b = (const float*)d_in[3];
    const float* a_w    = (const float*)d_in[4];
    float* out = (float*)d_out;

    char* ws = (char*)d_ws;
    short* h_bf   = (short*)(ws);                              // 2 MB
    short* hT_bf  = (short*)(ws + (2u << 20));                 // 2 MB
    short* a_srcb = (short*)(ws + (4u << 20));                 // 512 KB
    float* e2     = (float*)(ws + (4u << 20) + (512u << 10));  // 64 KB
    u64*   msk    = (u64*)  (ws + (5u << 20));                 // 2 MB
    float* part_m = (float*)(ws + (7u << 20));                 // 512 KB (S=8)
    float* part_l = (float*)(ws + (7u << 20) + (512u << 10));  // 512 KB
    float* part_y = (float*)(ws + (8u << 20));                 // S * 4 MB

    proj_kernel<<<N / 4, 256, 0, stream>>>(x, proj_w, proj_b, a_w, h_bf, a_srcb, e2);
    transpose_kernel<<<dim3(N / 64, B), 256, 0, stream>>>(h_bf, hT_bf);
    mask_kernel<<<N / 4, 256, 0, stream>>>(dist, msk);

    int S = 8;
    while (S > 1 && (8u << 20) + (size_t)S * B * N * C * 4 > ws_size) S >>= 1;
    bool direct = ((8u << 20) + (size_t)B * N * C * 4 > ws_size);

    if (direct) {
        attn_kernel<<<dim3(N / 32, 1), 256, 0, stream>>>(
            msk, h_bf, hT_bf, a_srcb, e2, out, part_m, part_l, N, 1);
    } else {
        attn_kernel<<<dim3(N / 32, S), 256, 0, stream>>>(
            msk, h_bf, hT_bf, a_srcb, e2, part_y, part_m, part_l, N / S, 0);
        combine_kernel<<<(B * N * C) / 256, 256, 0, stream>>>(part_y, part_m, part_l, out, S);
    }
}